// Round 7
// baseline (576.746 us; speedup 1.0000x reference)
//
#include <hip/hip_runtime.h>

typedef __bf16 bf16;
typedef bf16 bf16x8 __attribute__((ext_vector_type(8)));
typedef float f32x4 __attribute__((ext_vector_type(4)));

#define B_   4
#define N_   2048
#define DIM_ 1024
#define H_   16
#define DH_  64
#define M_   (B_ * N_)   // 8192

// log2(e) * (1/sqrt(64))
#define CEXP 0.18033688f

#define GLOBAL_CP(g) (const __attribute__((address_space(1))) void*)(g)
#define LDS_CP(l)    (__attribute__((address_space(3))) void*)(l)

// ---------------------------------------------------------------------------
// fp32 -> bf16 conversion (RTN), 4 elems/thread.
// ---------------------------------------------------------------------------
__global__ __launch_bounds__(256) void cvt_f32_bf16(
    const float* __restrict__ in, bf16* __restrict__ o, int n4)
{
    const int i = blockIdx.x * blockDim.x + threadIdx.x;
    if (i < n4) {
        const float4 v = ((const float4*)in)[i];
        union { bf16 h[4]; uint2 u; } r;
        r.h[0] = (bf16)v.x; r.h[1] = (bf16)v.y;
        r.h[2] = (bf16)v.z; r.h[3] = (bf16)v.w;
        ((uint2*)o)[i] = r.u;
    }
}

// ---------------------------------------------------------------------------
// GEMM: C[M x N] = A[M x K] @ B[N x K]^T   (bf16 in, fp32 acc)
// m97 structure: global_load_lds width=16 staging, unpadded [row][32] LDS,
// 2-barrier K-loop. 128x128 tile, BK=32, 4 waves (2x2) x 64x64.
// mode 0: write fp32 C row-major to outf
// mode 1: scatter to q/k [bh][n][d] (Q pre-scaled by CEXP) and
//         V TRANSPOSED [bh][d][n] (uint2-packed)
// ---------------------------------------------------------------------------
__global__ __launch_bounds__(256) void gemm_bt(
    const bf16* __restrict__ A, const bf16* __restrict__ Bm,
    int Ndim, int K, int mode,
    float* __restrict__ outf,
    bf16* __restrict__ qb, bf16* __restrict__ kbv, bf16* __restrict__ vbT)
{
    __shared__ bf16 As[128 * 32];   // 8192 B, contiguous (global_load_lds layout)
    __shared__ bf16 Bs[128 * 32];   // 8192 B

    const int tid  = threadIdx.x;
    const int wave = tid >> 6;
    const int lane = tid & 63;
    const int quad = lane >> 4;
    const int lr   = lane & 15;
    const int wr   = wave >> 1, wc = wave & 1;
    const int m0 = blockIdx.y * 128;
    const int n0 = blockIdx.x * 128;

    f32x4 acc[4][4];
#pragma unroll
    for (int i = 0; i < 4; i++)
#pragma unroll
        for (int j = 0; j < 4; j++) acc[i][j] = f32x4{0.f, 0.f, 0.f, 0.f};

    // staging map: wave issue j covers rows j*64 + wave*16 .. +15;
    // lane -> row (lane>>2), col (lane&3)*8.  LDS slot = base + lane*16B.
    const int srow = lane >> 2;
    const int scol = (lane & 3) * 8;

    for (int k0 = 0; k0 < K; k0 += 32) {
        __syncthreads();  // prev-iter frag reads done
#pragma unroll
        for (int j = 0; j < 2; j++) {
            const int rbase = j * 64 + wave * 16;
            __builtin_amdgcn_global_load_lds(
                GLOBAL_CP(A + (size_t)(m0 + rbase + srow) * K + k0 + scol),
                LDS_CP(&As[rbase * 32 + lane * 8]), 16, 0, 0);
            __builtin_amdgcn_global_load_lds(
                GLOBAL_CP(Bm + (size_t)(n0 + rbase + srow) * K + k0 + scol),
                LDS_CP(&Bs[rbase * 32 + lane * 8]), 16, 0, 0);
        }
        __syncthreads();  // staging visible (vmcnt drain)

        bf16x8 af[4], bfr[4];
#pragma unroll
        for (int i = 0; i < 4; i++)
            af[i] = *(const bf16x8*)(&As[(wr * 64 + i * 16 + lr) * 32 + quad * 8]);
#pragma unroll
        for (int j = 0; j < 4; j++)
            bfr[j] = *(const bf16x8*)(&Bs[(wc * 64 + j * 16 + lr) * 32 + quad * 8]);
#pragma unroll
        for (int i = 0; i < 4; i++)
#pragma unroll
            for (int j = 0; j < 4; j++)
                acc[i][j] = __builtin_amdgcn_mfma_f32_16x16x32_bf16(
                    af[i], bfr[j], acc[i][j], 0, 0, 0);
    }

#pragma unroll
    for (int i = 0; i < 4; i++) {
        const int mbase = m0 + wr * 64 + i * 16 + quad * 4;
#pragma unroll
        for (int j = 0; j < 4; j++) {
            const int n = n0 + wc * 64 + j * 16 + lr;
            if (mode == 0) {
#pragma unroll
                for (int r = 0; r < 4; r++)
                    outf[(size_t)(mbase + r) * Ndim + n] = acc[i][j][r];
            } else {
                const int which = n >> 10;
                const int h = (n >> 6) & 15;
                const int d = n & 63;
                const int b  = mbase >> 11;      // mbase..mbase+3 same b (4-aligned)
                const int t0 = mbase & 2047;
                if (which == 2) {
                    // V^T: [bh][d][n], 4 consecutive t -> one 8B store
                    union { uint2 u; bf16 hh[4]; } p;
#pragma unroll
                    for (int r = 0; r < 4; r++) p.hh[r] = (bf16)acc[i][j][r];
                    *(uint2*)(&vbT[(((size_t)(b * 16 + h)) * 64 + d) * 2048 + t0]) = p.u;
                } else {
                    bf16* dst = (which == 0) ? qb : kbv;
                    const float sc = (which == 0) ? CEXP : 1.0f;  // fold softmax scale into Q
#pragma unroll
                    for (int r = 0; r < 4; r++)
                        dst[(((size_t)(b * 16 + h)) * 2048 + t0 + r) * 64 + d] =
                            (bf16)(acc[i][j][r] * sc);
                }
            }
        }
    }
}

// ---------------------------------------------------------------------------
// Flash attention v5: R5 structure (1024 blocks, 128 q-rows/block) with
// Pb aliased into Ks (Ks dead after S^T within an iteration) -> LDS 34 KB ->
// 4 blocks/CU (16 waves/CU). Extra barrier between S^T reads and P writes.
// S^T = K Q^T; P^T b64 stores; Vs XOR-swizzled; Q pre-scaled by CEXP.
// ---------------------------------------------------------------------------
#define LDK 72     // Ks stride (elems)
#define LDP 40     // Pb stride (elems)

__global__ __launch_bounds__(256, 4) void attn_kernel(
    const bf16* __restrict__ qb, const bf16* __restrict__ kb,
    const bf16* __restrict__ vbT, bf16* __restrict__ ao)
{
    __shared__ bf16 Ks[128 * LDK];     // 18432 B (Pb aliases into this)
    __shared__ bf16 Vs[64 * 128];      // 16384 B  [d][key], 16B-chunk XOR swizzle
    bf16* Pb = Ks;                     // per-wave 32q x 32key slices, alias

    const int tid  = threadIdx.x;
    const int wave = tid >> 6;
    const int lane = tid & 63;
    const int quad = lane >> 4;
    const int lr   = lane & 15;

    // XCD swizzle: all 16 q-tiles of one head land on one XCD (bid % 8 heuristic)
    const int bid = blockIdx.x;
    const int qt  = (bid >> 3) & 15;
    const int bh  = ((bid >> 7) << 3) | (bid & 7);

    const bf16* Q  = qb  + (size_t)bh * N_ * DH_;
    const bf16* Kp = kb  + (size_t)bh * N_ * DH_;
    const bf16* Vp = vbT + (size_t)bh * DH_ * N_;   // [d][n]

    // Q fragments (B-operand of S^T MFMA)
    bf16x8 aq[2][2];
#pragma unroll
    for (int i = 0; i < 2; i++)
#pragma unroll
        for (int ks = 0; ks < 2; ks++)
            aq[i][ks] = *(const bf16x8*)(Q + (size_t)(qt * 128 + wave * 32 + i * 16 + lr) * DH_
                                           + ks * 32 + quad * 8);

    const int krow = tid >> 1;          // 0..127 (key)
    const int khf  = tid & 1;           // dh half
    const int vrow = tid >> 4;          // 0..15 (d), +16 per pass
    const int vchk = tid & 15;          // 16B chunk within 256B row
    const int pwb  = wave * 32 * LDP;

    // prefetch tile 0
    uint4 kr[4], vr[4];
    {
        const uint4* kg = (const uint4*)(Kp + (size_t)krow * DH_ + khf * 32);
#pragma unroll
        for (int c = 0; c < 4; c++) kr[c] = kg[c];
#pragma unroll
        for (int c = 0; c < 4; c++)
            vr[c] = *(const uint4*)(Vp + (size_t)(vrow + 16 * c) * N_ + vchk * 8);
    }

    float lrow[2] = {0.f, 0.f};
    f32x4 oacc[2][4];
#pragma unroll
    for (int i = 0; i < 2; i++)
#pragma unroll
        for (int jo = 0; jo < 4; jo++) oacc[i][jo] = f32x4{0.f, 0.f, 0.f, 0.f};

    for (int t = 0; t < N_ / 128; t++) {
        __syncthreads();   // A: prev-iter P/V readers done (Ks/Pb + Vs free)
        // stage K (natural) and V^T (vector, XOR-swizzled chunks)
#pragma unroll
        for (int c = 0; c < 4; c++)
            *(uint4*)(&Ks[krow * LDK + khf * 32 + c * 8]) = kr[c];
#pragma unroll
        for (int c = 0; c < 4; c++) {
            const int d = vrow + 16 * c;
            *(uint4*)(&Vs[d * 128 + ((vchk ^ (d & 7)) << 3)]) = vr[c];
        }
        __syncthreads();   // B: staging visible

        // S^T = K Q^T : D[key][q]; sacc[qi][kbi], key=kbi*16+quad*4+r, q=qi*16+lr
        f32x4 sacc[2][8];
#pragma unroll
        for (int i = 0; i < 2; i++)
#pragma unroll
            for (int j = 0; j < 8; j++) sacc[i][j] = f32x4{0.f, 0.f, 0.f, 0.f};
#pragma unroll
        for (int ks = 0; ks < 2; ks++)
#pragma unroll
            for (int kbi = 0; kbi < 8; kbi++) {
                bf16x8 ak = *(const bf16x8*)(&Ks[(kbi * 16 + lr) * LDK + ks * 32 + quad * 8]);
                sacc[0][kbi] = __builtin_amdgcn_mfma_f32_16x16x32_bf16(ak, aq[0][ks], sacc[0][kbi], 0, 0, 0);
                sacc[1][kbi] = __builtin_amdgcn_mfma_f32_16x16x32_bf16(ak, aq[1][ks], sacc[1][kbi], 0, 0, 0);
            }

        // softmax (Q pre-scaled -> plain exp2); in-lane sum + 2 shuffles
#pragma unroll
        for (int qi = 0; qi < 2; qi++) {
            float s = 0.f;
#pragma unroll
            for (int kbi = 0; kbi < 8; kbi++)
#pragma unroll
                for (int r = 0; r < 4; r++) {
                    const float p = exp2f(sacc[qi][kbi][r]);
                    sacc[qi][kbi][r] = p;
                    s += p;
                }
            s += __shfl_xor(s, 16);
            s += __shfl_xor(s, 32);
            lrow[qi] += s;
        }

        // prefetch tile t+1 (in flight across PV + next staging)
        if (t < N_ / 128 - 1) {
            const uint4* kg = (const uint4*)(Kp + (size_t)((t + 1) * 128 + krow) * DH_ + khf * 32);
#pragma unroll
            for (int c = 0; c < 4; c++) kr[c] = kg[c];
#pragma unroll
            for (int c = 0; c < 4; c++)
                vr[c] = *(const uint4*)(Vp + (size_t)(vrow + 16 * c) * N_
                                           + (t + 1) * 128 + vchk * 8);
        }

        __syncthreads();   // C: all waves done reading Ks -> safe to write Pb

        // O += P V in four key=32 slices through per-wave Pb (aliased in Ks)
#pragma unroll
        for (int kp = 0; kp < 4; kp++) {
#pragma unroll
            for (int qi = 0; qi < 2; qi++)
#pragma unroll
                for (int kk = 0; kk < 2; kk++) {
                    const int kbi = 2 * kp + kk;
                    union { uint2 u; bf16 hh[4]; } p;
#pragma unroll
                    for (int r = 0; r < 4; r++) p.hh[r] = (bf16)sacc[qi][kbi][r];
                    *(uint2*)(&Pb[pwb + (qi * 16 + lr) * LDP + kk * 16 + quad * 4]) = p.u;
                }
            asm volatile("s_waitcnt lgkmcnt(0)" ::: "memory");
            bf16x8 ap0 = *(const bf16x8*)(&Pb[pwb + lr * LDP + quad * 8]);
            bf16x8 ap1 = *(const bf16x8*)(&Pb[pwb + (16 + lr) * LDP + quad * 8]);
#pragma unroll
            for (int jo = 0; jo < 4; jo++) {
                const int d = jo * 16 + lr;
                bf16x8 bv = *(const bf16x8*)(&Vs[d * 128 + (((kp * 4 + quad) ^ (d & 7)) << 3)]);
                oacc[0][jo] = __builtin_amdgcn_mfma_f32_16x16x32_bf16(ap0, bv, oacc[0][jo], 0, 0, 0);
                oacc[1][jo] = __builtin_amdgcn_mfma_f32_16x16x32_bf16(ap1, bv, oacc[1][jo], 0, 0, 0);
            }
        }
    }

    // normalize: O rows q = i*16 + quad*4 + r; lrow quad-uniform, indexed by lr
    const int h = bh & 15;
    const int b = bh >> 4;
#pragma unroll
    for (int i = 0; i < 2; i++)
#pragma unroll
        for (int r = 0; r < 4; r++) {
            const float inv = 1.0f / __shfl(lrow[i], quad * 4 + r);
            const int qrow = qt * 128 + wave * 32 + i * 16 + quad * 4 + r;
#pragma unroll
            for (int jo = 0; jo < 4; jo++)
                ao[((size_t)(b * 2048 + qrow)) * 1024 + h * 64 + jo * 16 + lr] =
                    (bf16)(oacc[i][jo][r] * inv);
        }
}

// ---------------------------------------------------------------------------
extern "C" void kernel_launch(void* const* d_in, const int* in_sizes, int n_in,
                              void* d_out, int out_size, void* d_ws, size_t ws_size,
                              hipStream_t stream)
{
    const float* x     = (const float*)d_in[0];   // [8192 x 1024] fp32
    const float* wqkv  = (const float*)d_in[1];   // [3072 x 1024] fp32
    const float* wproj = (const float*)d_in[2];   // [1024 x 1024] fp32
    float* out = (float*)d_out;                   // [8192 x 1024] fp32

    const size_t nx  = (size_t)M_ * DIM_;
    const size_t nwq = (size_t)3 * DIM_ * DIM_;
    const size_t nwp = (size_t)DIM_ * DIM_;
    const size_t seg = (size_t)B_ * H_ * N_ * DH_;

    bf16* xb     = (bf16*)d_ws;        // dead after QKV gemm; ao overlays it
    bf16* wqkvb  = xb + nx;
    bf16* wprojb = wqkvb + nwq;
    bf16* qb     = wprojb + nwp;
    bf16* kb     = qb + seg;
    bf16* vbT    = kb + seg;           // [bh][d][n]
    bf16* ao     = xb;

    cvt_f32_bf16<<<(int)(nx  / 4 / 256), 256, 0, stream>>>(x, xb, (int)(nx / 4));
    cvt_f32_bf16<<<(int)(nwq / 4 / 256), 256, 0, stream>>>(wqkv, wqkvb, (int)(nwq / 4));
    cvt_f32_bf16<<<(int)(nwp / 4 / 256), 256, 0, stream>>>(wproj, wprojb, (int)(nwp / 4));

    gemm_bt<<<dim3(24, 64), 256, 0, stream>>>(xb, wqkvb, 3 * DIM_, DIM_, 1,
                                              nullptr, qb, kb, vbT);
    attn_kernel<<<dim3(1024), 256, 0, stream>>>(qb, kb, vbT, ao);
    gemm_bt<<<dim3(8, 64), 256, 0, stream>>>(ao, wprojb, DIM_, DIM_, 0,
                                             out, nullptr, nullptr, nullptr);
}

// Round 8
// 380.859 us; speedup vs baseline: 1.5143x; 1.5143x over previous
//
#include <hip/hip_runtime.h>

typedef __bf16 bf16;
typedef bf16 bf16x8 __attribute__((ext_vector_type(8)));
typedef float f32x4 __attribute__((ext_vector_type(4)));

#define B_   4
#define N_   2048
#define DIM_ 1024
#define H_   16
#define DH_  64
#define M_   (B_ * N_)   // 8192

// log2(e) * (1/sqrt(64))
#define CEXP 0.18033688f

#define GLOBAL_CP(g) (const __attribute__((address_space(1))) void*)(g)
#define LDS_CP(l)    (__attribute__((address_space(3))) void*)(l)

// ---------------------------------------------------------------------------
// fp32 -> bf16 conversion (RTN), 4 elems/thread.
// ---------------------------------------------------------------------------
__global__ __launch_bounds__(256) void cvt_f32_bf16(
    const float* __restrict__ in, bf16* __restrict__ o, int n4)
{
    const int i = blockIdx.x * blockDim.x + threadIdx.x;
    if (i < n4) {
        const float4 v = ((const float4*)in)[i];
        union { bf16 h[4]; uint2 u; } r;
        r.h[0] = (bf16)v.x; r.h[1] = (bf16)v.y;
        r.h[2] = (bf16)v.z; r.h[3] = (bf16)v.w;
        ((uint2*)o)[i] = r.u;
    }
}

// ---------------------------------------------------------------------------
// GEMM: C[M x N] = A[M x K] @ B[N x K]^T   (bf16 in, fp32 acc)
// m97 structure: global_load_lds width=16 staging, unpadded [row][32] LDS,
// 2-barrier K-loop. 128x128 tile, BK=32, 4 waves (2x2) x 64x64.
// mode 0: write fp32 C row-major to outf
// mode 1: scatter to q/k [bh][n][d] (Q pre-scaled by CEXP) and
//         V TRANSPOSED [bh][d][n] (uint2-packed)
// ---------------------------------------------------------------------------
__global__ __launch_bounds__(256) void gemm_bt(
    const bf16* __restrict__ A, const bf16* __restrict__ Bm,
    int Ndim, int K, int mode,
    float* __restrict__ outf,
    bf16* __restrict__ qb, bf16* __restrict__ kbv, bf16* __restrict__ vbT)
{
    __shared__ bf16 As[128 * 32];   // 8192 B, contiguous (global_load_lds layout)
    __shared__ bf16 Bs[128 * 32];   // 8192 B

    const int tid  = threadIdx.x;
    const int wave = tid >> 6;
    const int lane = tid & 63;
    const int quad = lane >> 4;
    const int lr   = lane & 15;
    const int wr   = wave >> 1, wc = wave & 1;
    const int m0 = blockIdx.y * 128;
    const int n0 = blockIdx.x * 128;

    f32x4 acc[4][4];
#pragma unroll
    for (int i = 0; i < 4; i++)
#pragma unroll
        for (int j = 0; j < 4; j++) acc[i][j] = f32x4{0.f, 0.f, 0.f, 0.f};

    // staging map: wave issue j covers rows j*64 + wave*16 .. +15;
    // lane -> row (lane>>2), col (lane&3)*8.  LDS slot = base + lane*16B.
    const int srow = lane >> 2;
    const int scol = (lane & 3) * 8;

    for (int k0 = 0; k0 < K; k0 += 32) {
        __syncthreads();  // prev-iter frag reads done
#pragma unroll
        for (int j = 0; j < 2; j++) {
            const int rbase = j * 64 + wave * 16;
            __builtin_amdgcn_global_load_lds(
                GLOBAL_CP(A + (size_t)(m0 + rbase + srow) * K + k0 + scol),
                LDS_CP(&As[rbase * 32 + lane * 8]), 16, 0, 0);
            __builtin_amdgcn_global_load_lds(
                GLOBAL_CP(Bm + (size_t)(n0 + rbase + srow) * K + k0 + scol),
                LDS_CP(&Bs[rbase * 32 + lane * 8]), 16, 0, 0);
        }
        __syncthreads();  // staging visible (vmcnt drain)

        bf16x8 af[4], bfr[4];
#pragma unroll
        for (int i = 0; i < 4; i++)
            af[i] = *(const bf16x8*)(&As[(wr * 64 + i * 16 + lr) * 32 + quad * 8]);
#pragma unroll
        for (int j = 0; j < 4; j++)
            bfr[j] = *(const bf16x8*)(&Bs[(wc * 64 + j * 16 + lr) * 32 + quad * 8]);
#pragma unroll
        for (int i = 0; i < 4; i++)
#pragma unroll
            for (int j = 0; j < 4; j++)
                acc[i][j] = __builtin_amdgcn_mfma_f32_16x16x32_bf16(
                    af[i], bfr[j], acc[i][j], 0, 0, 0);
    }

#pragma unroll
    for (int i = 0; i < 4; i++) {
        const int mbase = m0 + wr * 64 + i * 16 + quad * 4;
#pragma unroll
        for (int j = 0; j < 4; j++) {
            const int n = n0 + wc * 64 + j * 16 + lr;
            if (mode == 0) {
#pragma unroll
                for (int r = 0; r < 4; r++)
                    outf[(size_t)(mbase + r) * Ndim + n] = acc[i][j][r];
            } else {
                const int which = n >> 10;
                const int h = (n >> 6) & 15;
                const int d = n & 63;
                const int b  = mbase >> 11;      // mbase..mbase+3 same b (4-aligned)
                const int t0 = mbase & 2047;
                if (which == 2) {
                    // V^T: [bh][d][n], 4 consecutive t -> one 8B store
                    union { uint2 u; bf16 hh[4]; } p;
#pragma unroll
                    for (int r = 0; r < 4; r++) p.hh[r] = (bf16)acc[i][j][r];
                    *(uint2*)(&vbT[(((size_t)(b * 16 + h)) * 64 + d) * 2048 + t0]) = p.u;
                } else {
                    bf16* dst = (which == 0) ? qb : kbv;
                    const float sc = (which == 0) ? CEXP : 1.0f;  // fold softmax scale into Q
#pragma unroll
                    for (int r = 0; r < 4; r++)
                        dst[(((size_t)(b * 16 + h)) * 2048 + t0 + r) * 64 + d] =
                            (bf16)(acc[i][j][r] * sc);
                }
            }
        }
    }
}

// ---------------------------------------------------------------------------
// Flash attention v6: R5 structure (1024 blocks, 128 q-rows/block), Pb
// aliased into Ks -> LDS 34 KB. __launch_bounds__(256,3): VGPR stays ~84
// (no spill; R7's (256,4) forced VGPR 64 -> 1.8 GB scratch traffic), and
// hardware occupancy = min(LDS 4, VGPR 6) = 4 blocks/CU.
// S^T = K Q^T; P^T b64 stores; Vs XOR-swizzled; Q pre-scaled by CEXP.
// ---------------------------------------------------------------------------
#define LDK 72     // Ks stride (elems)
#define LDP 40     // Pb stride (elems)

__global__ __launch_bounds__(256, 3) void attn_kernel(
    const bf16* __restrict__ qb, const bf16* __restrict__ kb,
    const bf16* __restrict__ vbT, bf16* __restrict__ ao)
{
    __shared__ bf16 Ks[128 * LDK];     // 18432 B (Pb aliases into this)
    __shared__ bf16 Vs[64 * 128];      // 16384 B  [d][key], 16B-chunk XOR swizzle
    bf16* Pb = Ks;                     // per-wave 32q x 32key slices, alias

    const int tid  = threadIdx.x;
    const int wave = tid >> 6;
    const int lane = tid & 63;
    const int quad = lane >> 4;
    const int lr   = lane & 15;

    // XCD swizzle: all 16 q-tiles of one head land on one XCD (bid % 8 heuristic)
    const int bid = blockIdx.x;
    const int qt  = (bid >> 3) & 15;
    const int bh  = ((bid >> 7) << 3) | (bid & 7);

    const bf16* Q  = qb  + (size_t)bh * N_ * DH_;
    const bf16* Kp = kb  + (size_t)bh * N_ * DH_;
    const bf16* Vp = vbT + (size_t)bh * DH_ * N_;   // [d][n]

    // Q fragments (B-operand of S^T MFMA)
    bf16x8 aq[2][2];
#pragma unroll
    for (int i = 0; i < 2; i++)
#pragma unroll
        for (int ks = 0; ks < 2; ks++)
            aq[i][ks] = *(const bf16x8*)(Q + (size_t)(qt * 128 + wave * 32 + i * 16 + lr) * DH_
                                           + ks * 32 + quad * 8);

    const int krow = tid >> 1;          // 0..127 (key)
    const int khf  = tid & 1;           // dh half
    const int vrow = tid >> 4;          // 0..15 (d), +16 per pass
    const int vchk = tid & 15;          // 16B chunk within 256B row
    const int pwb  = wave * 32 * LDP;

    // prefetch tile 0
    uint4 kr[4], vr[4];
    {
        const uint4* kg = (const uint4*)(Kp + (size_t)krow * DH_ + khf * 32);
#pragma unroll
        for (int c = 0; c < 4; c++) kr[c] = kg[c];
#pragma unroll
        for (int c = 0; c < 4; c++)
            vr[c] = *(const uint4*)(Vp + (size_t)(vrow + 16 * c) * N_ + vchk * 8);
    }

    float lrow[2] = {0.f, 0.f};
    f32x4 oacc[2][4];
#pragma unroll
    for (int i = 0; i < 2; i++)
#pragma unroll
        for (int jo = 0; jo < 4; jo++) oacc[i][jo] = f32x4{0.f, 0.f, 0.f, 0.f};

    for (int t = 0; t < N_ / 128; t++) {
        __syncthreads();   // A: prev-iter P/V readers done (Ks/Pb + Vs free)
        // stage K (natural) and V^T (vector, XOR-swizzled chunks)
#pragma unroll
        for (int c = 0; c < 4; c++)
            *(uint4*)(&Ks[krow * LDK + khf * 32 + c * 8]) = kr[c];
#pragma unroll
        for (int c = 0; c < 4; c++) {
            const int d = vrow + 16 * c;
            *(uint4*)(&Vs[d * 128 + ((vchk ^ (d & 7)) << 3)]) = vr[c];
        }
        __syncthreads();   // B: staging visible

        // S^T = K Q^T : D[key][q]; sacc[qi][kbi], key=kbi*16+quad*4+r, q=qi*16+lr
        f32x4 sacc[2][8];
#pragma unroll
        for (int i = 0; i < 2; i++)
#pragma unroll
            for (int j = 0; j < 8; j++) sacc[i][j] = f32x4{0.f, 0.f, 0.f, 0.f};
#pragma unroll
        for (int ks = 0; ks < 2; ks++)
#pragma unroll
            for (int kbi = 0; kbi < 8; kbi++) {
                bf16x8 ak = *(const bf16x8*)(&Ks[(kbi * 16 + lr) * LDK + ks * 32 + quad * 8]);
                sacc[0][kbi] = __builtin_amdgcn_mfma_f32_16x16x32_bf16(ak, aq[0][ks], sacc[0][kbi], 0, 0, 0);
                sacc[1][kbi] = __builtin_amdgcn_mfma_f32_16x16x32_bf16(ak, aq[1][ks], sacc[1][kbi], 0, 0, 0);
            }

        // softmax (Q pre-scaled -> plain exp2); in-lane sum + 2 shuffles
#pragma unroll
        for (int qi = 0; qi < 2; qi++) {
            float s = 0.f;
#pragma unroll
            for (int kbi = 0; kbi < 8; kbi++)
#pragma unroll
                for (int r = 0; r < 4; r++) {
                    const float p = exp2f(sacc[qi][kbi][r]);
                    sacc[qi][kbi][r] = p;
                    s += p;
                }
            s += __shfl_xor(s, 16);
            s += __shfl_xor(s, 32);
            lrow[qi] += s;
        }

        // prefetch tile t+1 (in flight across PV + next staging)
        if (t < N_ / 128 - 1) {
            const uint4* kg = (const uint4*)(Kp + (size_t)((t + 1) * 128 + krow) * DH_ + khf * 32);
#pragma unroll
            for (int c = 0; c < 4; c++) kr[c] = kg[c];
#pragma unroll
            for (int c = 0; c < 4; c++)
                vr[c] = *(const uint4*)(Vp + (size_t)(vrow + 16 * c) * N_
                                           + (t + 1) * 128 + vchk * 8);
        }

        __syncthreads();   // C: all waves done reading Ks -> safe to write Pb

        // O += P V in four key=32 slices through per-wave Pb (aliased in Ks)
#pragma unroll
        for (int kp = 0; kp < 4; kp++) {
#pragma unroll
            for (int qi = 0; qi < 2; qi++)
#pragma unroll
                for (int kk = 0; kk < 2; kk++) {
                    const int kbi = 2 * kp + kk;
                    union { uint2 u; bf16 hh[4]; } p;
#pragma unroll
                    for (int r = 0; r < 4; r++) p.hh[r] = (bf16)sacc[qi][kbi][r];
                    *(uint2*)(&Pb[pwb + (qi * 16 + lr) * LDP + kk * 16 + quad * 4]) = p.u;
                }
            asm volatile("s_waitcnt lgkmcnt(0)" ::: "memory");
            bf16x8 ap0 = *(const bf16x8*)(&Pb[pwb + lr * LDP + quad * 8]);
            bf16x8 ap1 = *(const bf16x8*)(&Pb[pwb + (16 + lr) * LDP + quad * 8]);
#pragma unroll
            for (int jo = 0; jo < 4; jo++) {
                const int d = jo * 16 + lr;
                bf16x8 bv = *(const bf16x8*)(&Vs[d * 128 + (((kp * 4 + quad) ^ (d & 7)) << 3)]);
                oacc[0][jo] = __builtin_amdgcn_mfma_f32_16x16x32_bf16(ap0, bv, oacc[0][jo], 0, 0, 0);
                oacc[1][jo] = __builtin_amdgcn_mfma_f32_16x16x32_bf16(ap1, bv, oacc[1][jo], 0, 0, 0);
            }
        }
    }

    // normalize: O rows q = i*16 + quad*4 + r; lrow quad-uniform, indexed by lr
    const int h = bh & 15;
    const int b = bh >> 4;
#pragma unroll
    for (int i = 0; i < 2; i++)
#pragma unroll
        for (int r = 0; r < 4; r++) {
            const float inv = 1.0f / __shfl(lrow[i], quad * 4 + r);
            const int qrow = qt * 128 + wave * 32 + i * 16 + quad * 4 + r;
#pragma unroll
            for (int jo = 0; jo < 4; jo++)
                ao[((size_t)(b * 2048 + qrow)) * 1024 + h * 64 + jo * 16 + lr] =
                    (bf16)(oacc[i][jo][r] * inv);
        }
}

// ---------------------------------------------------------------------------
extern "C" void kernel_launch(void* const* d_in, const int* in_sizes, int n_in,
                              void* d_out, int out_size, void* d_ws, size_t ws_size,
                              hipStream_t stream)
{
    const float* x     = (const float*)d_in[0];   // [8192 x 1024] fp32
    const float* wqkv  = (const float*)d_in[1];   // [3072 x 1024] fp32
    const float* wproj = (const float*)d_in[2];   // [1024 x 1024] fp32
    float* out = (float*)d_out;                   // [8192 x 1024] fp32

    const size_t nx  = (size_t)M_ * DIM_;
    const size_t nwq = (size_t)3 * DIM_ * DIM_;
    const size_t nwp = (size_t)DIM_ * DIM_;
    const size_t seg = (size_t)B_ * H_ * N_ * DH_;

    bf16* xb     = (bf16*)d_ws;        // dead after QKV gemm; ao overlays it
    bf16* wqkvb  = xb + nx;
    bf16* wprojb = wqkvb + nwq;
    bf16* qb     = wprojb + nwp;
    bf16* kb     = qb + seg;
    bf16* vbT    = kb + seg;           // [bh][d][n]
    bf16* ao     = xb;

    cvt_f32_bf16<<<(int)(nx  / 4 / 256), 256, 0, stream>>>(x, xb, (int)(nx / 4));
    cvt_f32_bf16<<<(int)(nwq / 4 / 256), 256, 0, stream>>>(wqkv, wqkvb, (int)(nwq / 4));
    cvt_f32_bf16<<<(int)(nwp / 4 / 256), 256, 0, stream>>>(wproj, wprojb, (int)(nwp / 4));

    gemm_bt<<<dim3(24, 64), 256, 0, stream>>>(xb, wqkvb, 3 * DIM_, DIM_, 1,
                                              nullptr, qb, kb, vbT);
    attn_kernel<<<dim3(1024), 256, 0, stream>>>(qb, kb, vbT, ao);
    gemm_bt<<<dim3(8, 64), 256, 0, stream>>>(ao, wprojb, DIM_, DIM_, 0,
                                             out, nullptr, nullptr, nullptr);
}